// Round 1
// baseline (526.502 us; speedup 1.0000x reference)
//
#include <hip/hip_runtime.h>

// RipEncoding: project 262144 gaussians onto 10 planes, anisotropic ripmap
// (8x8 level grid) quadrilinear interpolation of 16-dim features.
//
// d_in[0] = means (N,3) f32; d_in[1] = covs (N,3,3) f32;
// d_in[2] = fm (10,512,512,16) f32.  d_out = (N, 160) f32.
// d_ws holds the 63 pooled planes (plane (0,0) == fm is read in place):
// needed = 778256 px/vertex * 10 * 16 * 4 B = 498,083,840 bytes.

#define NV 10
#define FD 16
#define NS 262144
#define TV 778256L   // 1020*1020 - 512*512 pixels per vertex in ws

// P matrices (row0 = p0, row1 = p1), precomputed in float64 per reference.
__constant__ float c_P[NV][2][3] = {
  {{-0.7071067811865476f, 0.7071067811865476f, 0.0f},
   {-0.4082482904638631f,-0.4082482904638631f, 0.8164965809277261f}},
  {{-0.7071067811865476f, 0.7071067811865476f, 0.0f},
   { 0.4082482904638631f, 0.4082482904638631f, 0.8164965809277261f}},
  {{ 0.7071067811865476f, 0.7071067811865476f, 0.0f},
   {-0.4082482904638631f, 0.4082482904638631f, 0.8164965809277261f}},
  {{ 0.7071067811865476f, 0.7071067811865476f, 0.0f},
   { 0.4082482904638631f,-0.4082482904638631f, 0.8164965809277261f}},
  {{-1.0f, 0.0f, 0.0f},
   { 0.0f,-0.3568220897730899f, 0.9341723589627157f}},
  {{-1.0f, 0.0f, 0.0f},
   { 0.0f, 0.3568220897730899f, 0.9341723589627157f}},
  {{ 0.0f, 1.0f, 0.0f},
   {-0.9341723589627157f, 0.0f, 0.3568220897730899f}},
  {{ 0.0f, 1.0f, 0.0f},
   { 0.9341723589627157f, 0.0f, 0.3568220897730899f}},
  {{-0.3568220897730899f, 0.9341723589627157f, 0.0f},
   { 0.0f, 0.0f, 1.0f}},
  {{ 0.3568220897730899f, 0.9341723589627157f, 0.0f},
   { 0.0f, 0.0f, 1.0f}},
};

// cumulative widths: CW[l] = sum_{l'<l} (512>>l')
__constant__ int c_CW[8] = {0, 512, 768, 896, 960, 992, 1008, 1016};

// pixel offset of plane (l1,l2) inside the ws pyramid (excludes plane (0,0))
__device__ __forceinline__ long offp(int l1, int l2) {
  return 1020L * (long)c_CW[l1] + (long)(512 >> l1) * (long)c_CW[l2] - 262144L;
}

// ---- width pooling: out(l1,0)[y][x] = 0.5*(in(l1-1,0)[y][2x] + [y][2x+1]) ----
__global__ void pool_w_kernel(const float* __restrict__ in, float* __restrict__ out,
                              long inStrideV, long outStrideV,
                              long inOffPx, long outOffPx, int lwOut)
{
  int t = blockIdx.x * blockDim.x + threadIdx.x;
  int Wout = 1 << lwOut;
  int total = NV * 512 * Wout * 4;
  if (t >= total) return;
  int q = t & 3;                       // feature quad
  int x = (t >> 2) & (Wout - 1);
  int y = (t >> (2 + lwOut)) & 511;
  int v = t >> (11 + lwOut);
  long inPix = (long)v * inStrideV + inOffPx + (long)y * (Wout << 1) + (x << 1);
  const float4* pin = (const float4*)(in + inPix * FD);
  float4 a = pin[q];
  float4 b = pin[q + 4];               // next pixel (same row)
  float4 r;
  r.x = 0.5f * (a.x + b.x); r.y = 0.5f * (a.y + b.y);
  r.z = 0.5f * (a.z + b.z); r.w = 0.5f * (a.w + b.w);
  long outPix = (long)v * outStrideV + outOffPx + (long)y * Wout + x;
  ((float4*)(out + outPix * FD))[q] = r;
}

// ---- height pooling for one l2, all l1 at once ----
__global__ void pool_h_kernel(const float* __restrict__ fm, float* __restrict__ ws, int l2)
{
  int H = 512 >> l2;
  int total = NV * H * 1020 * 4;
  int t = blockIdx.x * blockDim.x + threadIdx.x;
  if (t >= total) return;
  int q = t & 3;
  int idx = t >> 2;
  int c = idx % 1020;                  // virtual column across all l1 planes
  int r2 = idx / 1020;
  int y = r2 & (H - 1);
  int v = r2 >> (9 - l2);
  int l1 = 0;
  #pragma unroll
  for (int i = 1; i < 8; ++i) l1 += (c >= c_CW[i]) ? 1 : 0;
  int x = c - c_CW[l1];
  int W = 512 >> l1;
  const float* pin;
  long inPix;
  if (l1 == 0 && l2 == 1) {            // parent is plane (0,0) == fm
    pin = fm + (long)v * (262144L * FD);
    inPix = (long)(2 * y) * W + x;
  } else {
    pin = ws + (long)v * (TV * FD);
    inPix = offp(l1, l2 - 1) + (long)(2 * y) * W + x;
  }
  float4 a = ((const float4*)(pin + inPix * FD))[q];
  float4 b = ((const float4*)(pin + (inPix + W) * FD))[q];
  float4 r;
  r.x = 0.5f * (a.x + b.x); r.y = 0.5f * (a.y + b.y);
  r.z = 0.5f * (a.z + b.z); r.w = 0.5f * (a.w + b.w);
  long outPix = (long)v * TV + offp(l1, l2) + (long)y * W + x;
  ((float4*)(ws + outPix * FD))[q] = r;
}

// ---- interpolation: 4 threads per (n,v) pair, one feature-quad each ----
__global__ void interp_kernel(const float* __restrict__ means,
                              const float* __restrict__ covs,
                              const float* __restrict__ fm,
                              const float* __restrict__ ws,
                              float* __restrict__ out)
{
  int t = blockIdx.x * blockDim.x + threadIdx.x;
  if (t >= NS * NV * 4) return;
  int q = t & 3;
  int pair = t >> 2;
  int v = pair % NV;
  int n = pair / NV;

  float m0 = means[3 * n], m1 = means[3 * n + 1], m2 = means[3 * n + 2];
  const float* C = covs + 9L * n;
  float c0 = C[0], c1 = C[1], c2 = C[2];
  float c3 = C[3], c4 = C[4], c5 = C[5];
  float c6 = C[6], c7 = C[7], c8 = C[8];
  float p00 = c_P[v][0][0], p01 = c_P[v][0][1], p02 = c_P[v][0][2];
  float p10 = c_P[v][1][0], p11 = c_P[v][1][1], p12 = c_P[v][1][2];

  float cx = m0 * p00 + m1 * p01 + m2 * p02;
  float cy = m0 * p10 + m1 * p11 + m2 * p12;

  float t0 = c0 * p00 + c1 * p01 + c2 * p02;
  float t1 = c3 * p00 + c4 * p01 + c5 * p02;
  float t2 = c6 * p00 + c7 * p01 + c8 * p02;
  float s2x = p00 * t0 + p01 * t1 + p02 * t2;
  t0 = c0 * p10 + c1 * p11 + c2 * p12;
  t1 = c3 * p10 + c4 * p11 + c5 * p12;
  t2 = c6 * p10 + c7 * p11 + c8 * p12;
  float s2y = p10 * t0 + p11 * t1 + p12 * t2;

  // level = log2(sqrt(max(s2,1e-20))) + log2(512), clipped [0,7]
  float lx = 0.5f * log2f(fmaxf(s2x, 1e-20f)) + 9.0f;
  float ly = 0.5f * log2f(fmaxf(s2y, 1e-20f)) + 9.0f;
  lx = fminf(fmaxf(lx, 0.0f), 7.0f);
  ly = fminf(fmaxf(ly, 0.0f), 7.0f);
  int l1f = (int)lx;                 // lx in [0,7] -> trunc == floor
  int l2f = (int)ly;
  float wx = lx - (float)l1f;
  float wy = ly - (float)l2f;
  int l1c = (l1f < 7) ? l1f + 1 : 7;
  int l2c = (l2f < 7) ? l2f + 1 : 7;

  float ax = 0.f, ay = 0.f, az = 0.f, aw = 0.f;

  #pragma unroll
  for (int i = 0; i < 2; ++i) {
    int l1 = i ? l1c : l1f;
    float wl1 = i ? wx : 1.0f - wx;
    int Wl = 512 >> l1;
    float u = (cx * 0.5f + 0.5f) * (float)Wl - 0.5f;
    float uf = floorf(u);
    float fu = u - uf;
    int iu = (int)uf;
    int ix0 = min(max(iu, 0), Wl - 1);
    int ix1 = min(max(iu + 1, 0), Wl - 1);
    #pragma unroll
    for (int j = 0; j < 2; ++j) {
      int l2 = j ? l2c : l2f;
      float wl2 = j ? wy : 1.0f - wy;
      int Hl = 512 >> l2;
      float vv = (cy * 0.5f + 0.5f) * (float)Hl - 0.5f;
      float vf = floorf(vv);
      float fv = vv - vf;
      int iv = (int)vf;
      int iy0 = min(max(iv, 0), Hl - 1);
      int iy1 = min(max(iv + 1, 0), Hl - 1);

      const float* plane;
      if ((l1 | l2) == 0) plane = fm + (long)v * (262144L * FD);
      else                plane = ws + ((long)v * TV + offp(l1, l2)) * FD;

      float w   = wl1 * wl2;
      float w00 = w * (1.0f - fu) * (1.0f - fv);
      float w10 = w * fu * (1.0f - fv);
      float w01 = w * (1.0f - fu) * fv;
      float w11 = w * fu * fv;

      const float4* r0 = (const float4*)(plane + (long)iy0 * Wl * FD);
      const float4* r1 = (const float4*)(plane + (long)iy1 * Wl * FD);
      float4 ta = r0[ix0 * 4 + q];
      float4 tb = r0[ix1 * 4 + q];
      float4 tc = r1[ix0 * 4 + q];
      float4 td = r1[ix1 * 4 + q];

      ax += w00 * ta.x + w10 * tb.x + w01 * tc.x + w11 * td.x;
      ay += w00 * ta.y + w10 * tb.y + w01 * tc.y + w11 * td.y;
      az += w00 * ta.z + w10 * tb.z + w01 * tc.z + w11 * td.z;
      aw += w00 * ta.w + w10 * tb.w + w01 * tc.w + w11 * td.w;
    }
  }

  float4 r; r.x = ax; r.y = ay; r.z = az; r.w = aw;
  ((float4*)(out + (long)pair * FD))[q] = r;
}

extern "C" void kernel_launch(void* const* d_in, const int* in_sizes, int n_in,
                              void* d_out, int out_size, void* d_ws, size_t ws_size,
                              hipStream_t stream)
{
  const float* means = (const float*)d_in[0];
  const float* covs  = (const float*)d_in[1];
  const float* fm    = (const float*)d_in[2];
  float* out = (float*)d_out;
  float* ws  = (float*)d_ws;

  static const int CW[8] = {0, 512, 768, 896, 960, 992, 1008, 1016};
  auto offpH = [&](int l1, int l2) -> long {
    return 1020L * CW[l1] + (long)(512 >> l1) * CW[l2] - 262144L;
  };

  const int BS = 256;

  // 1) width pools: plane (l1,0) from (l1-1,0); (0,0) is fm itself.
  for (int l1 = 1; l1 <= 7; ++l1) {
    int lw = 9 - l1;
    int total = NV * 512 * (1 << lw) * 4;
    const float* in = (l1 == 1) ? fm : ws;
    long inStride = (l1 == 1) ? 262144L : TV;
    long inOff = (l1 == 1) ? 0L : offpH(l1 - 1, 0);
    long outOff = offpH(l1, 0);
    pool_w_kernel<<<(total + BS - 1) / BS, BS, 0, stream>>>(
        in, ws, inStride, TV, inOff, outOff, lw);
  }

  // 2) height pools: for each l2, all l1 planes at once.
  for (int l2 = 1; l2 <= 7; ++l2) {
    int total = NV * (512 >> l2) * 1020 * 4;
    pool_h_kernel<<<(total + BS - 1) / BS, BS, 0, stream>>>(fm, ws, l2);
  }

  // 3) quadrilinear interpolation.
  {
    int total = NS * NV * 4;
    interp_kernel<<<(total + BS - 1) / BS, BS, 0, stream>>>(means, covs, fm, ws, out);
  }
}

// Round 3
// 401.165 us; speedup vs baseline: 1.3124x; 1.3124x over previous
//
#include <hip/hip_runtime.h>
#include <hip/hip_fp16.h>

// RipEncoding, round 2b: fp16 pyramid (incl. level (0,0)), fused 2-pass build,
// precomputed per-(n,v) projections, 2-threads-per-pair gather interp.
//
// ws layout: [0, 332928000) fp16 pyramid (10 verts x 1020x1020 px x 16 halfs)
//            [332928000, +41943040) float4 proj table [v][n] = (cx,cy,lx,ly)

#define NV 10
#define FD 16
#define NS 262144
#define PYR_PX 1040400L   // 1020*1020 pixels per vertex
#define PYR_BYTES 332928000L

__constant__ float c_P[NV][2][3] = {
  {{-0.7071067811865476f, 0.7071067811865476f, 0.0f},
   {-0.4082482904638631f,-0.4082482904638631f, 0.8164965809277261f}},
  {{-0.7071067811865476f, 0.7071067811865476f, 0.0f},
   { 0.4082482904638631f, 0.4082482904638631f, 0.8164965809277261f}},
  {{ 0.7071067811865476f, 0.7071067811865476f, 0.0f},
   {-0.4082482904638631f, 0.4082482904638631f, 0.8164965809277261f}},
  {{ 0.7071067811865476f, 0.7071067811865476f, 0.0f},
   { 0.4082482904638631f,-0.4082482904638631f, 0.8164965809277261f}},
  {{-1.0f, 0.0f, 0.0f},
   { 0.0f,-0.3568220897730899f, 0.9341723589627157f}},
  {{-1.0f, 0.0f, 0.0f},
   { 0.0f, 0.3568220897730899f, 0.9341723589627157f}},
  {{ 0.0f, 1.0f, 0.0f},
   {-0.9341723589627157f, 0.0f, 0.3568220897730899f}},
  {{ 0.0f, 1.0f, 0.0f},
   { 0.9341723589627157f, 0.0f, 0.3568220897730899f}},
  {{-0.3568220897730899f, 0.9341723589627157f, 0.0f},
   { 0.0f, 0.0f, 1.0f}},
  {{ 0.3568220897730899f, 0.9341723589627157f, 0.0f},
   { 0.0f, 0.0f, 1.0f}},
};

__constant__ int c_CW[8]  = {0, 512, 768, 896, 960, 992, 1008, 1016};
__constant__ int c_SCW[8] = {0, 256, 384, 448, 480, 496, 504, 508};

// pixel offset of plane (l1,l2) inside a vertex's pyramid (includes (0,0))
__device__ __forceinline__ long offp(int l1, int l2) {
  return 1020L * (long)c_CW[l1] + (long)(512 >> l1) * (long)c_CW[l2];
}

__device__ __forceinline__ uint2 pack4(float4 f) {
  __half2 h0 = __floats2half2_rn(f.x, f.y);
  __half2 h1 = __floats2half2_rn(f.z, f.w);
  uint2 s;
  s.x = *(unsigned int*)&h0;
  s.y = *(unsigned int*)&h1;
  return s;
}

// ---- pass 1: one block per (v, y) row; all 8 width levels from LDS ----
__global__ __launch_bounds__(256) void build_w(const float* __restrict__ fm,
                                               __half* __restrict__ pyr)
{
  __shared__ float4 lds[512 * 5];   // pixel p, quad fb at lds[p*5+fb]; 40 KB
  int b = blockIdx.x;
  int v = b >> 9, y = b & 511;
  int t = threadIdx.x;
  const float4* src = (const float4*)(fm + ((long)v * 262144L + (long)y * 512) * FD);
  #pragma unroll
  for (int i = 0; i < 8; ++i) {
    int u = t + 256 * i;                        // linear float4 index 0..2047
    float4 d = src[u];
    lds[(u >> 2) * 5 + (u & 3)] = d;
  }
  __syncthreads();
  __half* bv = pyr + (long)v * PYR_PX * FD;
  {                                             // level (0,0): convert row
    uint2* dst = (uint2*)(bv + (long)y * 512 * FD);
    #pragma unroll
    for (int i = 0; i < 8; ++i) {
      int u = t + 256 * i;
      dst[u] = pack4(lds[(u >> 2) * 5 + (u & 3)]);
    }
  }
  #pragma unroll
  for (int l1 = 1; l1 <= 7; ++l1) {
    int W = 512 >> l1;
    int units = W * 4;
    float4 r[4];
    #pragma unroll
    for (int i = 0; i < 4; ++i) {
      int u = t + 256 * i;
      if (u < units) {
        int px = u >> 2, fb = u & 3;
        float4 a = lds[(2 * px) * 5 + fb];
        float4 c = lds[(2 * px + 1) * 5 + fb];
        r[i].x = 0.5f * (a.x + c.x); r[i].y = 0.5f * (a.y + c.y);
        r[i].z = 0.5f * (a.z + c.z); r[i].w = 0.5f * (a.w + c.w);
      }
    }
    __syncthreads();
    uint2* dst = (uint2*)(bv + (offp(l1, 0) + (long)y * W) * FD);
    #pragma unroll
    for (int i = 0; i < 4; ++i) {
      int u = t + 256 * i;
      if (u < units) {
        int px = u >> 2, fb = u & 3;
        lds[px * 5 + fb] = r[i];
        dst[u] = pack4(r[i]);
      }
    }
    __syncthreads();
  }
}

// ---- pass 2: one block per (v, l1, 2-col strip); all 7 height levels ----
__global__ __launch_bounds__(256) void build_h(__half* __restrict__ pyr)
{
  __shared__ uint4 lds[512 * 5];    // row r, 16B-slot k at lds[r*5+k]; 40 KB
  int b = blockIdx.x;
  int v = b / 510, rs = b % 510;
  int l1 = 0;
  #pragma unroll
  for (int i = 1; i < 8; ++i) l1 += (rs >= c_SCW[i]) ? 1 : 0;
  int s = rs - c_SCW[l1];
  int W = 512 >> l1;
  int c0 = 2 * s;
  int t = threadIdx.x;
  __half* bv = pyr + (long)v * PYR_PX * FD;
  const __half* p0 = bv + offp(l1, 0) * FD;
  #pragma unroll
  for (int i = 0; i < 8; ++i) {
    int u = t + 256 * i;                         // r = u>>2, k = u&3
    int r = u >> 2, k = u & 3;
    lds[r * 5 + k] = ((const uint4*)(p0 + ((long)r * W + c0) * FD))[k];
  }
  __syncthreads();
  #pragma unroll
  for (int l2 = 1; l2 <= 7; ++l2) {
    int H = 512 >> l2;
    int units = H * 4;
    uint4 r4[4];
    #pragma unroll
    for (int i = 0; i < 4; ++i) {
      int u = t + 256 * i;
      if (u < units) {
        int r = u >> 2, k = u & 3;
        uint4 a = lds[(2 * r) * 5 + k];
        uint4 c = lds[(2 * r + 1) * 5 + k];
        __half2* ha = (__half2*)&a;
        __half2* hc = (__half2*)&c;
        uint4 res;
        __half2* hr = (__half2*)&res;
        #pragma unroll
        for (int j = 0; j < 4; ++j) {
          float2 fa = __half22float2(ha[j]);
          float2 fc = __half22float2(hc[j]);
          hr[j] = __floats2half2_rn(0.5f * (fa.x + fc.x), 0.5f * (fa.y + fc.y));
        }
        r4[i] = res;
      }
    }
    __syncthreads();
    __half* dst = bv + offp(l1, l2) * FD;
    #pragma unroll
    for (int i = 0; i < 4; ++i) {
      int u = t + 256 * i;
      if (u < units) {
        int r = u >> 2, k = u & 3;
        lds[r * 5 + k] = r4[i];
        ((uint4*)(dst + ((long)r * W + c0) * FD))[k] = r4[i];
      }
    }
    __syncthreads();
  }
}

// ---- projection/level precompute: one thread per sample ----
__global__ __launch_bounds__(256) void proj_kernel(const float* __restrict__ means,
                                                   const float* __restrict__ covs,
                                                   float4* __restrict__ pl)
{
  int n = blockIdx.x * 256 + threadIdx.x;
  if (n >= NS) return;
  float m0 = means[3 * n], m1 = means[3 * n + 1], m2 = means[3 * n + 2];
  const float* C = covs + 9L * n;
  float c0 = C[0], c1 = C[1], c2 = C[2];
  float c3 = C[3], c4 = C[4], c5 = C[5];
  float c6 = C[6], c7 = C[7], c8 = C[8];
  #pragma unroll
  for (int v = 0; v < NV; ++v) {
    float p00 = c_P[v][0][0], p01 = c_P[v][0][1], p02 = c_P[v][0][2];
    float p10 = c_P[v][1][0], p11 = c_P[v][1][1], p12 = c_P[v][1][2];
    float cx = m0 * p00 + m1 * p01 + m2 * p02;
    float cy = m0 * p10 + m1 * p11 + m2 * p12;
    float t0 = c0 * p00 + c1 * p01 + c2 * p02;
    float t1 = c3 * p00 + c4 * p01 + c5 * p02;
    float t2 = c6 * p00 + c7 * p01 + c8 * p02;
    float s2x = p00 * t0 + p01 * t1 + p02 * t2;
    t0 = c0 * p10 + c1 * p11 + c2 * p12;
    t1 = c3 * p10 + c4 * p11 + c5 * p12;
    t2 = c6 * p10 + c7 * p11 + c8 * p12;
    float s2y = p10 * t0 + p11 * t1 + p12 * t2;
    float lx = 0.5f * log2f(fmaxf(s2x, 1e-20f)) + 9.0f;
    float ly = 0.5f * log2f(fmaxf(s2y, 1e-20f)) + 9.0f;
    lx = fminf(fmaxf(lx, 0.0f), 7.0f);
    ly = fminf(fmaxf(ly, 0.0f), 7.0f);
    pl[(long)v * NS + n] = make_float4(cx, cy, lx, ly);
  }
}

__device__ __forceinline__ void acc8(const __half* p, float w, float* acc) {
  uint4 d = *(const uint4*)p;
  const __half2* h = (const __half2*)&d;
  #pragma unroll
  for (int j = 0; j < 4; ++j) {
    float2 f = __half22float2(h[j]);
    acc[2 * j]     += w * f.x;
    acc[2 * j + 1] += w * f.y;
  }
}

// ---- interp: 2 threads per (n,v) pair, 8 features each ----
__global__ __launch_bounds__(256) void interp2(const float4* __restrict__ pl,
                                               const __half* __restrict__ pyr,
                                               float* __restrict__ out)
{
  int t = blockIdx.x * 256 + threadIdx.x;
  int q = t & 1;
  int pair = t >> 1;
  if (pair >= NS * NV) return;
  int v = pair % NV;
  int n = pair / NV;
  float4 p = pl[(long)v * NS + n];
  float cx = p.x, cy = p.y, lx = p.z, ly = p.w;
  int l1f = (int)lx;                 // lx,ly already clipped to [0,7]
  int l2f = (int)ly;
  float wx = lx - (float)l1f;
  float wy = ly - (float)l2f;
  int l1c = (l1f < 7) ? l1f + 1 : 7;
  int l2c = (l2f < 7) ? l2f + 1 : 7;

  const __half* bvq = pyr + (long)v * PYR_PX * FD + q * 8;
  float acc[8] = {0.f, 0.f, 0.f, 0.f, 0.f, 0.f, 0.f, 0.f};

  #pragma unroll
  for (int i = 0; i < 2; ++i) {
    int l1 = i ? l1c : l1f;
    float wl1 = i ? wx : 1.0f - wx;
    int Wl = 512 >> l1;
    float u = (cx * 0.5f + 0.5f) * (float)Wl - 0.5f;
    float uf = floorf(u);
    float fu = u - uf;
    int iu = (int)uf;
    int ix0 = min(max(iu, 0), Wl - 1);
    int ix1 = min(max(iu + 1, 0), Wl - 1);
    #pragma unroll
    for (int j = 0; j < 2; ++j) {
      int l2 = j ? l2c : l2f;
      float wl2 = j ? wy : 1.0f - wy;
      int Hl = 512 >> l2;
      float vv = (cy * 0.5f + 0.5f) * (float)Hl - 0.5f;
      float vf = floorf(vv);
      float fv = vv - vf;
      int iv = (int)vf;
      int iy0 = min(max(iv, 0), Hl - 1);
      int iy1 = min(max(iv + 1, 0), Hl - 1);

      const __half* plane = bvq + offp(l1, l2) * FD;
      float w   = wl1 * wl2;
      float w00 = w * (1.0f - fu) * (1.0f - fv);
      float w10 = w * fu * (1.0f - fv);
      float w01 = w * (1.0f - fu) * fv;
      float w11 = w * fu * fv;

      acc8(plane + ((long)iy0 * Wl + ix0) * FD, w00, acc);
      acc8(plane + ((long)iy0 * Wl + ix1) * FD, w10, acc);
      acc8(plane + ((long)iy1 * Wl + ix0) * FD, w01, acc);
      acc8(plane + ((long)iy1 * Wl + ix1) * FD, w11, acc);
    }
  }

  float4* o = (float4*)(out + (long)pair * FD + q * 8);
  float4 o0 = make_float4(acc[0], acc[1], acc[2], acc[3]);
  float4 o1 = make_float4(acc[4], acc[5], acc[6], acc[7]);
  o[0] = o0;
  o[1] = o1;
}

extern "C" void kernel_launch(void* const* d_in, const int* in_sizes, int n_in,
                              void* d_out, int out_size, void* d_ws, size_t ws_size,
                              hipStream_t stream)
{
  const float* means = (const float*)d_in[0];
  const float* covs  = (const float*)d_in[1];
  const float* fm    = (const float*)d_in[2];
  float* out = (float*)d_out;
  __half* pyr = (__half*)d_ws;
  float4* pl  = (float4*)((char*)d_ws + PYR_BYTES);

  build_w<<<NV * 512, 256, 0, stream>>>(fm, pyr);
  build_h<<<NV * 510, 256, 0, stream>>>(pyr);
  proj_kernel<<<(NS + 255) / 256, 256, 0, stream>>>(means, covs, pl);

  int total = NS * NV * 2;
  interp2<<<(total + 255) / 256, 256, 0, stream>>>(pl, pyr, out);
}

// Round 4
// 347.821 us; speedup vs baseline: 1.5137x; 1.1534x over previous
//
#include <hip/hip_runtime.h>
#include <hip/hip_fp16.h>

// RipEncoding, round 4: fp16 pyramid, fused width-pass build, coalesced
// per-level height pools, v-major + XCD-chunked gather interp.
//
// ws layout: [0, 332928000) fp16 pyramid (10 verts x 1020x1020 px x 16 halfs)
//            [332928000, +41943040) float4 proj table [v][n] = (cx,cy,lx,ly)

#define NV 10
#define FD 16
#define NS 262144          // 2^18
#define PYR_PX 1040400L    // 1020*1020 pixels per vertex
#define PYR_BYTES 332928000L

__constant__ float c_P[NV][2][3] = {
  {{-0.7071067811865476f, 0.7071067811865476f, 0.0f},
   {-0.4082482904638631f,-0.4082482904638631f, 0.8164965809277261f}},
  {{-0.7071067811865476f, 0.7071067811865476f, 0.0f},
   { 0.4082482904638631f, 0.4082482904638631f, 0.8164965809277261f}},
  {{ 0.7071067811865476f, 0.7071067811865476f, 0.0f},
   {-0.4082482904638631f, 0.4082482904638631f, 0.8164965809277261f}},
  {{ 0.7071067811865476f, 0.7071067811865476f, 0.0f},
   { 0.4082482904638631f,-0.4082482904638631f, 0.8164965809277261f}},
  {{-1.0f, 0.0f, 0.0f},
   { 0.0f,-0.3568220897730899f, 0.9341723589627157f}},
  {{-1.0f, 0.0f, 0.0f},
   { 0.0f, 0.3568220897730899f, 0.9341723589627157f}},
  {{ 0.0f, 1.0f, 0.0f},
   {-0.9341723589627157f, 0.0f, 0.3568220897730899f}},
  {{ 0.0f, 1.0f, 0.0f},
   { 0.9341723589627157f, 0.0f, 0.3568220897730899f}},
  {{-0.3568220897730899f, 0.9341723589627157f, 0.0f},
   { 0.0f, 0.0f, 1.0f}},
  {{ 0.3568220897730899f, 0.9341723589627157f, 0.0f},
   { 0.0f, 0.0f, 1.0f}},
};

__constant__ int c_CW[8] = {0, 512, 768, 896, 960, 992, 1008, 1016};

// pixel offset of plane (l1,l2) inside a vertex's pyramid (includes (0,0))
__device__ __forceinline__ long offp(int l1, int l2) {
  return 1020L * (long)c_CW[l1] + (long)(512 >> l1) * (long)c_CW[l2];
}

__device__ __forceinline__ uint2 pack4(float4 f) {
  __half2 h0 = __floats2half2_rn(f.x, f.y);
  __half2 h1 = __floats2half2_rn(f.z, f.w);
  uint2 s;
  s.x = *(unsigned int*)&h0;
  s.y = *(unsigned int*)&h1;
  return s;
}

// ---- pass 1: one block per (v, y) row; all 8 width levels from LDS ----
__global__ __launch_bounds__(256) void build_w(const float* __restrict__ fm,
                                               __half* __restrict__ pyr)
{
  __shared__ float4 lds[512 * 5];   // pixel p, quad fb at lds[p*5+fb]; 40 KB
  int b = blockIdx.x;
  int v = b >> 9, y = b & 511;
  int t = threadIdx.x;
  const float4* src = (const float4*)(fm + ((long)v * 262144L + (long)y * 512) * FD);
  #pragma unroll
  for (int i = 0; i < 8; ++i) {
    int u = t + 256 * i;                        // linear float4 index 0..2047
    float4 d = src[u];
    lds[(u >> 2) * 5 + (u & 3)] = d;
  }
  __syncthreads();
  __half* bv = pyr + (long)v * PYR_PX * FD;
  {                                             // level (0,0): convert row
    uint2* dst = (uint2*)(bv + (long)y * 512 * FD);
    #pragma unroll
    for (int i = 0; i < 8; ++i) {
      int u = t + 256 * i;
      dst[u] = pack4(lds[(u >> 2) * 5 + (u & 3)]);
    }
  }
  #pragma unroll
  for (int l1 = 1; l1 <= 7; ++l1) {
    int W = 512 >> l1;
    int units = W * 4;
    float4 r[4];
    #pragma unroll
    for (int i = 0; i < 4; ++i) {
      int u = t + 256 * i;
      if (u < units) {
        int px = u >> 2, fb = u & 3;
        float4 a = lds[(2 * px) * 5 + fb];
        float4 c = lds[(2 * px + 1) * 5 + fb];
        r[i].x = 0.5f * (a.x + c.x); r[i].y = 0.5f * (a.y + c.y);
        r[i].z = 0.5f * (a.z + c.z); r[i].w = 0.5f * (a.w + c.w);
      }
    }
    __syncthreads();
    uint2* dst = (uint2*)(bv + (offp(l1, 0) + (long)y * W) * FD);
    #pragma unroll
    for (int i = 0; i < 4; ++i) {
      int u = t + 256 * i;
      if (u < units) {
        int px = u >> 2, fb = u & 3;
        lds[px * 5 + fb] = r[i];
        dst[u] = pack4(r[i]);
      }
    }
    __syncthreads();
  }
}

// ---- pass 2: per-level height pool, fully coalesced (7 launches) ----
// out(l1,l2)[y][x] = avg(in(l1,l2-1)[2y][x], [2y+1][x]); unit = 16B half-pixel.
__global__ __launch_bounds__(256) void pool_h(__half* __restrict__ pyr, int l2)
{
  int H = 512 >> l2;
  int total = NV * H * 2040;          // units: 1020 px * 2 slots per virtual row
  int t = blockIdx.x * 256 + threadIdx.x;
  if (t >= total) return;
  int u = t % 2040;
  int r2 = t / 2040;
  int c = u >> 1, k = u & 1;          // virtual column, 16B slot
  int y = r2 & (H - 1);
  int v = r2 >> (9 - l2);
  int l1 = 0;
  #pragma unroll
  for (int i = 1; i < 8; ++i) l1 += (c >= c_CW[i]) ? 1 : 0;
  int x = c - c_CW[l1];
  int W = 512 >> l1;
  __half* bv = pyr + (long)v * PYR_PX * FD;
  const __half* src = bv + offp(l1, l2 - 1) * FD;
  uint4 a = *(const uint4*)(src + ((long)(2 * y) * W + x) * FD + k * 8);
  uint4 b = *(const uint4*)(src + ((long)(2 * y + 1) * W + x) * FD + k * 8);
  const __half2* ha = (const __half2*)&a;
  const __half2* hb = (const __half2*)&b;
  uint4 res;
  __half2* hr = (__half2*)&res;
  #pragma unroll
  for (int j = 0; j < 4; ++j) {
    float2 fa = __half22float2(ha[j]);
    float2 fb = __half22float2(hb[j]);
    hr[j] = __floats2half2_rn(0.5f * (fa.x + fb.x), 0.5f * (fa.y + fb.y));
  }
  *(uint4*)(bv + offp(l1, l2) * FD + ((long)y * W + x) * FD + k * 8) = res;
}

// ---- projection/level precompute: one thread per sample ----
__global__ __launch_bounds__(256) void proj_kernel(const float* __restrict__ means,
                                                   const float* __restrict__ covs,
                                                   float4* __restrict__ pl)
{
  int n = blockIdx.x * 256 + threadIdx.x;
  if (n >= NS) return;
  float m0 = means[3 * n], m1 = means[3 * n + 1], m2 = means[3 * n + 2];
  const float* C = covs + 9L * n;
  float c0 = C[0], c1 = C[1], c2 = C[2];
  float c3 = C[3], c4 = C[4], c5 = C[5];
  float c6 = C[6], c7 = C[7], c8 = C[8];
  #pragma unroll
  for (int v = 0; v < NV; ++v) {
    float p00 = c_P[v][0][0], p01 = c_P[v][0][1], p02 = c_P[v][0][2];
    float p10 = c_P[v][1][0], p11 = c_P[v][1][1], p12 = c_P[v][1][2];
    float cx = m0 * p00 + m1 * p01 + m2 * p02;
    float cy = m0 * p10 + m1 * p11 + m2 * p12;
    float t0 = c0 * p00 + c1 * p01 + c2 * p02;
    float t1 = c3 * p00 + c4 * p01 + c5 * p02;
    float t2 = c6 * p00 + c7 * p01 + c8 * p02;
    float s2x = p00 * t0 + p01 * t1 + p02 * t2;
    t0 = c0 * p10 + c1 * p11 + c2 * p12;
    t1 = c3 * p10 + c4 * p11 + c5 * p12;
    t2 = c6 * p10 + c7 * p11 + c8 * p12;
    float s2y = p10 * t0 + p11 * t1 + p12 * t2;
    float lx = 0.5f * log2f(fmaxf(s2x, 1e-20f)) + 9.0f;
    float ly = 0.5f * log2f(fmaxf(s2y, 1e-20f)) + 9.0f;
    lx = fminf(fmaxf(lx, 0.0f), 7.0f);
    ly = fminf(fmaxf(ly, 0.0f), 7.0f);
    pl[(long)v * NS + n] = make_float4(cx, cy, lx, ly);
  }
}

__device__ __forceinline__ void acc8(const __half* p, float w, float* acc) {
  uint4 d = *(const uint4*)p;
  const __half2* h = (const __half2*)&d;
  #pragma unroll
  for (int j = 0; j < 4; ++j) {
    float2 f = __half22float2(h[j]);
    acc[2 * j]     += w * f.x;
    acc[2 * j + 1] += w * f.y;
  }
}

// ---- interp: v-major, 2 threads/pair, XCD-chunked block swizzle ----
// thread t = ((v2*NS + n)*2 + vlow)*2 + q ; v = 2*v2 + vlow.
// grid = 5*2^20 threads = 20480 blocks (divisible by 8 -> bijective swizzle).
__global__ __launch_bounds__(256) void interp3(const float4* __restrict__ pl,
                                               const __half* __restrict__ pyr,
                                               float* __restrict__ out)
{
  int bid = blockIdx.x;
  int swz = (bid & 7) * 2560 + (bid >> 3);    // 20480/8 = 2560 blocks per XCD
  int t = swz * 256 + threadIdx.x;
  int q = t & 1;
  int vlow = (t >> 1) & 1;
  int n = (t >> 2) & (NS - 1);
  int v2 = t >> 20;
  int v = v2 * 2 + vlow;

  float4 p = pl[(long)v * NS + n];
  float cx = p.x, cy = p.y, lx = p.z, ly = p.w;
  int l1f = (int)lx;                 // lx,ly already clipped to [0,7]
  int l2f = (int)ly;
  float wx = lx - (float)l1f;
  float wy = ly - (float)l2f;
  int l1c = (l1f < 7) ? l1f + 1 : 7;
  int l2c = (l2f < 7) ? l2f + 1 : 7;

  const __half* bvq = pyr + (long)v * PYR_PX * FD + q * 8;
  float acc[8] = {0.f, 0.f, 0.f, 0.f, 0.f, 0.f, 0.f, 0.f};

  #pragma unroll
  for (int i = 0; i < 2; ++i) {
    int l1 = i ? l1c : l1f;
    float wl1 = i ? wx : 1.0f - wx;
    int Wl = 512 >> l1;
    float u = (cx * 0.5f + 0.5f) * (float)Wl - 0.5f;
    float uf = floorf(u);
    float fu = u - uf;
    int iu = (int)uf;
    int ix0 = min(max(iu, 0), Wl - 1);
    int ix1 = min(max(iu + 1, 0), Wl - 1);
    #pragma unroll
    for (int j = 0; j < 2; ++j) {
      int l2 = j ? l2c : l2f;
      float wl2 = j ? wy : 1.0f - wy;
      int Hl = 512 >> l2;
      float vv = (cy * 0.5f + 0.5f) * (float)Hl - 0.5f;
      float vf = floorf(vv);
      float fv = vv - vf;
      int iv = (int)vf;
      int iy0 = min(max(iv, 0), Hl - 1);
      int iy1 = min(max(iv + 1, 0), Hl - 1);

      const __half* plane = bvq + offp(l1, l2) * FD;
      float w   = wl1 * wl2;
      float w00 = w * (1.0f - fu) * (1.0f - fv);
      float w10 = w * fu * (1.0f - fv);
      float w01 = w * (1.0f - fu) * fv;
      float w11 = w * fu * fv;

      acc8(plane + ((long)iy0 * Wl + ix0) * FD, w00, acc);
      acc8(plane + ((long)iy0 * Wl + ix1) * FD, w10, acc);
      acc8(plane + ((long)iy1 * Wl + ix0) * FD, w01, acc);
      acc8(plane + ((long)iy1 * Wl + ix1) * FD, w11, acc);
    }
  }

  float4* o = (float4*)(out + ((long)n * NV + v) * FD + q * 8);
  float4 o0 = make_float4(acc[0], acc[1], acc[2], acc[3]);
  float4 o1 = make_float4(acc[4], acc[5], acc[6], acc[7]);
  o[0] = o0;
  o[1] = o1;
}

extern "C" void kernel_launch(void* const* d_in, const int* in_sizes, int n_in,
                              void* d_out, int out_size, void* d_ws, size_t ws_size,
                              hipStream_t stream)
{
  const float* means = (const float*)d_in[0];
  const float* covs  = (const float*)d_in[1];
  const float* fm    = (const float*)d_in[2];
  float* out = (float*)d_out;
  __half* pyr = (__half*)d_ws;
  float4* pl  = (float4*)((char*)d_ws + PYR_BYTES);

  build_w<<<NV * 512, 256, 0, stream>>>(fm, pyr);
  for (int l2 = 1; l2 <= 7; ++l2) {
    int total = NV * (512 >> l2) * 2040;
    pool_h<<<(total + 255) / 256, 256, 0, stream>>>(pyr, l2);
  }
  proj_kernel<<<(NS + 255) / 256, 256, 0, stream>>>(means, covs, pl);

  interp3<<<20480, 256, 0, stream>>>(pl, pyr, out);
}